// Round 5
// baseline (609.987 us; speedup 1.0000x reference)
//
#include <hip/hip_runtime.h>

#define NN 100000
#define NE 200000
#define DN 128
#define DE 16
#define NR 3
#define NEDGE (NR * NE)         // 600000
#define NB1 98                  // scan1 blocks: 1024 elems each >= NN
#define NSTRIP 6250             // NN / 16 exactly

typedef __attribute__((ext_vector_type(8))) short short8;
typedef __attribute__((ext_vector_type(4))) float f32x4;

__device__ __forceinline__ unsigned short f2bf(float f) {
    unsigned int u = __float_as_uint(f);
    u = (u + 0x7fffu + ((u >> 16) & 1u)) >> 16;   // RNE
    return (unsigned short)u;
}

// ---------------------------------------------------------------------------
// prep: Wt[m] = bf16(W_m^T), stored PRE-SWIZZLED (chunk XOR) so gemm's LDS
//       copy is linear and ds_read_b128 is bank-conflict-free:
//         Wt[m*16384 + n*128 + ((k>>3)^(n&7))*8 + (k&7)] = bf16(W_m[k][n])
//       Wea[n][k] = bf16(We_{k/16}[k%16][n]) for k<48, 0-pad k=48..63
//       + dst histogram; tmp[eid] = rank within dst (fill needs NO atomics)
// ---------------------------------------------------------------------------
__global__ __launch_bounds__(256) void prep_kernel(
    const float* __restrict__ W_self, const float* __restrict__ W_rel,
    const float* __restrict__ We,
    unsigned short* __restrict__ Wt, unsigned short* __restrict__ Wea,
    const int* __restrict__ ei, unsigned* __restrict__ cur,
    unsigned char* __restrict__ tmp)
{
    const int id = blockIdx.x * 256 + threadIdx.x;   // grid 1024*256 = 262144
    if (id < 65536) {
        const int m = id >> 14, rem = id & 16383;
        const int k = rem >> 7, n = rem & 127;
        const float* src = (m == 0) ? W_self : (W_rel + (size_t)(m - 1) * 16384);
        Wt[m * 16384 + n * 128 + (((k >> 3) ^ (n & 7)) << 3) + (k & 7)] =
            f2bf(src[k * 128 + n]);
    } else if (id < 65536 + 8192) {
        const int wid = id - 65536;
        const int n = wid >> 6, k = wid & 63;
        const float v = (k < 48) ? We[(k >> 4) * 2048 + (k & 15) * 128 + n] : 0.f;
        Wea[n * 64 + k] = f2bf(v);
    }
    const int2* ei2 = (const int2*)ei;
    for (int eid = id; eid < NEDGE; eid += 262144) {
        const int2 e = ei2[eid];
        const unsigned pos = atomicAdd(&cur[e.y], 1u);
        tmp[eid] = (unsigned char)pos;   // max degree ~30 << 256
    }
}

// ---------------------------------------------------------------------------
// MFMA GEMM: B in LDS (staged once/block), A streamed with 1-strip prefetch.
//   grid 4096 = 4 matrices x 1024 strip-slices; block 256 thr = 4 waves, all
//   on matrix (bid & 3). B-frag ds_read uses the prep-side XOR swizzle ->
//   ~2-way banks (free). VGPR ~110 -> 3-4 waves/SIMD (vs 2 with reg-B).
// ---------------------------------------------------------------------------
__global__ __launch_bounds__(256, 3) void gemm_kernel(
    const float* __restrict__ x,
    const unsigned short* __restrict__ Wt,
    unsigned short* __restrict__ zb,
    unsigned short* __restrict__ y)
{
    __shared__ __align__(16) unsigned short Bs[128 * 128];   // 32 KB
    const int tid = threadIdx.x;
    const int m = blockIdx.x & 3;
    const int sblk = blockIdx.x >> 2;        // 0..1023
    const int lane = tid & 63;
    const int lm = lane & 15;
    const int lq = lane >> 4;

    // stage matrix m (linear copy; array is pre-swizzled in global)
    {
        const uint4* wp4 = (const uint4*)(Wt + (size_t)m * 16384);
        #pragma unroll
        for (int i = 0; i < 8; ++i)
            *(uint4*)&Bs[(tid + i * 256) * 8] = wp4[tid + i * 256];
    }
    __syncthreads();

    unsigned short* outp = (m == 0) ? zb : (y + (size_t)(m - 1) * NN * 128);

    int s = sblk;
    float4 xb[8];
    {
        const float* xp = x + (size_t)(s * 16 + lm) * 128 + lq * 8;
        #pragma unroll
        for (int ks = 0; ks < 4; ++ks) {
            xb[2 * ks]     = *(const float4*)(xp + ks * 32);
            xb[2 * ks + 1] = *(const float4*)(xp + ks * 32 + 4);
        }
    }

    while (true) {
        short8 af[4];
        #pragma unroll
        for (int ks = 0; ks < 4; ++ks) {
            short8 t;
            t[0] = f2bf(xb[2 * ks].x);     t[1] = f2bf(xb[2 * ks].y);
            t[2] = f2bf(xb[2 * ks].z);     t[3] = f2bf(xb[2 * ks].w);
            t[4] = f2bf(xb[2 * ks + 1].x); t[5] = f2bf(xb[2 * ks + 1].y);
            t[6] = f2bf(xb[2 * ks + 1].z); t[7] = f2bf(xb[2 * ks + 1].w);
            af[ks] = t;
        }
        const int sn = s + 1024;
        if (sn < NSTRIP) {
            const float* xp = x + (size_t)(sn * 16 + lm) * 128 + lq * 8;
            #pragma unroll
            for (int ks = 0; ks < 4; ++ks) {
                xb[2 * ks]     = *(const float4*)(xp + ks * 32);
                xb[2 * ks + 1] = *(const float4*)(xp + ks * 32 + 4);
            }
        }
        f32x4 acc[8];
        #pragma unroll
        for (int cg = 0; cg < 8; ++cg) acc[cg] = (f32x4){0.f, 0.f, 0.f, 0.f};
        #pragma unroll
        for (int cg = 0; cg < 8; ++cg)
            #pragma unroll
            for (int ks = 0; ks < 4; ++ks) {
                // logical B row n=cg*16+lm, chunk ks*4+lq, XOR-swizzled
                const short8 bf = *(const short8*)
                    &Bs[(cg * 16 + lm) * 128 + (((ks * 4 + lq) ^ (lm & 7)) << 3)];
                acc[cg] = __builtin_amdgcn_mfma_f32_16x16x32_bf16(bf, af[ks], acc[cg], 0, 0, 0);
            }
        unsigned short* rp = outp + (size_t)(s * 16 + lm) * 128 + lq * 4;
        #pragma unroll
        for (int cg = 0; cg < 8; ++cg) {
            ushort4 o;
            o.x = f2bf(acc[cg][0]); o.y = f2bf(acc[cg][1]);
            o.z = f2bf(acc[cg][2]); o.w = f2bf(acc[cg][3]);
            *(ushort4*)(rp + cg * 16) = o;
        }
        if (sn >= NSTRIP) break;
        s = sn;
    }
}

// ---------------------------------------------------------------------------
// CSR build: scan1 + merged scan2/3 (each block redundantly scans bsum)
// ---------------------------------------------------------------------------
__global__ __launch_bounds__(256) void scan1_kernel(
    const unsigned* __restrict__ cnt, unsigned* __restrict__ offs,
    unsigned* __restrict__ bsum)
{
    __shared__ unsigned wtot[4];
    const int tid = threadIdx.x, lane = tid & 63, wv = tid >> 6;
    const int base = blockIdx.x * 1024 + tid * 4;
    unsigned c[4];
    #pragma unroll
    for (int j = 0; j < 4; ++j) c[j] = (base + j < NN) ? cnt[base + j] : 0u;
    const unsigned ts = c[0] + c[1] + c[2] + c[3];
    unsigned incl = ts;
    #pragma unroll
    for (int d = 1; d < 64; d <<= 1) {
        unsigned v = __shfl_up(incl, d, 64);
        if (lane >= d) incl += v;
    }
    if (lane == 63) wtot[wv] = incl;
    __syncthreads();
    unsigned woff = 0;
    for (int p = 0; p < 4; ++p) if (p < wv) woff += wtot[p];
    unsigned run = woff + incl - ts;
    #pragma unroll
    for (int j = 0; j < 4; ++j) {
        if (base + j < NN) offs[base + j] = run;
        run += c[j];
    }
    if (tid == 255) bsum[blockIdx.x] = woff + incl;
}

__global__ __launch_bounds__(256) void scan23_kernel(
    unsigned* __restrict__ offs, const unsigned* __restrict__ bsum)
{
    __shared__ unsigned add_s;
    const int tid = threadIdx.x;
    if (tid < 64) {
        const int lane = tid;
        const unsigned v0 = (2 * lane     < NB1) ? bsum[2 * lane]     : 0u;
        const unsigned v1 = (2 * lane + 1 < NB1) ? bsum[2 * lane + 1] : 0u;
        const unsigned s = v0 + v1;
        unsigned incl = s;
        #pragma unroll
        for (int d = 1; d < 64; d <<= 1) {
            unsigned t = __shfl_up(incl, d, 64);
            if (lane >= d) incl += t;
        }
        const unsigned run = incl - s;           // exclusive prefix at 2*lane
        if (lane == (blockIdx.x >> 1))
            add_s = (blockIdx.x & 1) ? (run + v0) : run;
    }
    __syncthreads();
    const unsigned add = add_s;
    const int base = blockIdx.x * 1024 + tid * 4;
    #pragma unroll
    for (int j = 0; j < 4; ++j)
        if (base + j < NN) offs[base + j] += add;
    if (blockIdx.x == 0 && tid == 0) offs[NN] = NEDGE;
}

__global__ __launch_bounds__(256) void fill_kernel(
    const int* __restrict__ ei, const unsigned* __restrict__ offs,
    const unsigned char* __restrict__ tmp, uint2* __restrict__ elist)
{
    const int eid = blockIdx.x * 256 + threadIdx.x;
    if (eid < NEDGE) {
        const int2 e = ((const int2*)ei)[eid];
        const unsigned r = (eid >= 2 * NE) ? 2u : (eid >= NE ? 1u : 0u);
        const unsigned pos = offs[e.y] + (unsigned)tmp[eid];
        elist[pos] = make_uint2(r * NN + (unsigned)e.x, (unsigned)eid);
    }
}

// ---------------------------------------------------------------------------
// Fused aggregate (absorbs eaz): block = 4 waves = 16 dsts.
//   Phase A (per wave, 4 dsts): batched y-gathers (col = 2*lane view) AND
//     edge_attr reduction (g = lane>>4 rel group, k16 = lane&15 view) from
//     one elist walk; offs/elist via wave-uniform scalar loads.
//   Phase B: eaS[16][72] bf16 + ysumS[16][132] f32 staged in LDS (padded,
//     ~2-way banks); per wave 2 col-groups of the [16x64]@[64x128] Wea MFMA;
//     out = relu(z + ysum + ea@We + b) written as float4.
//   Removes: eaz dispatch, zb RMW (51 MB), duplicate CSR walk.
// ---------------------------------------------------------------------------
__global__ __launch_bounds__(256, 4) void aggregate_kernel(
    const unsigned short* __restrict__ zb,
    const unsigned short* __restrict__ y,      // [3*NN][128] bf16
    const float* __restrict__ edge_attr,       // [NEDGE][16]
    const unsigned short* __restrict__ Wea,    // [128][64] bf16
    const float* __restrict__ b,
    const unsigned* __restrict__ offs,         // [NN+1]
    const uint2* __restrict__ elist,
    float* __restrict__ out)
{
    __shared__ __align__(16) unsigned short eaS[16][72];
    __shared__ __align__(16) float ysumS[16][132];
    const int tid = threadIdx.x;
    const int wv = tid >> 6, lane = tid & 63;
    const int row0 = blockIdx.x * 16;             // grid 6250, exact
    const int dst0 = row0 + wv * 4;
    const int col = 2 * lane;
    const int k16 = lane & 15;
    const int g = lane >> 4;                      // rel group; 3 = zero pad

    unsigned sI[4], eI[4];
    #pragma unroll
    for (int d = 0; d < 4; ++d) {
        sI[d] = __builtin_amdgcn_readfirstlane(offs[dst0 + d]);
        eI[d] = __builtin_amdgcn_readfirstlane(offs[dst0 + d + 1]);
    }

    // batched edge metadata (scalar loads, contiguous 64B per dst)
    unsigned r[4][8], q[4][8];
    #pragma unroll
    for (int d = 0; d < 4; ++d) {
        const uint2* ep = elist + sI[d];          // +8 pad allocated
        #pragma unroll
        for (int j = 0; j < 8; ++j) {
            const uint2 p = ep[j];
            r[d][j] = (p.x < 3u * NN) ? p.x : 0u;
            q[d][j] = (p.y < (unsigned)NEDGE) ? p.y : 0u;
        }
    }

    // batched gathers: 32 y-loads then 32 attr-loads in flight
    unsigned v[4][8];
    #pragma unroll
    for (int d = 0; d < 4; ++d)
        #pragma unroll
        for (int j = 0; j < 8; ++j)
            v[d][j] = *(const unsigned*)(y + (size_t)r[d][j] * 128 + col);
    float a[4][8];
    #pragma unroll
    for (int d = 0; d < 4; ++d)
        #pragma unroll
        for (int j = 0; j < 8; ++j)
            a[d][j] = edge_attr[(size_t)q[d][j] * 16 + k16];

    float acc0[4], acc1[4], ea[4];
    #pragma unroll
    for (int d = 0; d < 4; ++d) {
        const unsigned zv = *(const unsigned*)(zb + (size_t)(dst0 + d) * 128 + col);
        acc0[d] = __uint_as_float(zv << 16);
        acc1[d] = __uint_as_float(zv & 0xffff0000u);
        ea[d] = 0.f;
    }

    #pragma unroll
    for (int d = 0; d < 4; ++d)
        #pragma unroll
        for (int j = 0; j < 8; ++j) {
            const bool live = (sI[d] + (unsigned)j) < eI[d];
            const unsigned vv = live ? v[d][j] : 0u;
            acc0[d] += __uint_as_float(vv << 16);
            acc1[d] += __uint_as_float(vv & 0xffff0000u);
            const bool okr = live && q[d][j] >= (unsigned)(g * NE)
                                  && q[d][j] < (unsigned)((g + 1) * NE);
            ea[d] += okr ? a[d][j] : 0.f;
        }

    // tails (deg > 8)
    #pragma unroll
    for (int d = 0; d < 4; ++d)
        for (unsigned i = sI[d] + 8; i < eI[d]; ++i) {
            const uint2 p = elist[i];
            const unsigned vv = *(const unsigned*)(y + (size_t)p.x * 128 + col);
            const float aa = edge_attr[(size_t)p.y * 16 + k16];
            acc0[d] += __uint_as_float(vv << 16);
            acc1[d] += __uint_as_float(vv & 0xffff0000u);
            const bool okr = p.y >= (unsigned)(g * NE) && p.y < (unsigned)((g + 1) * NE);
            ea[d] += okr ? aa : 0.f;
        }

    #pragma unroll
    for (int d = 0; d < 4; ++d) {
        eaS[wv * 4 + d][lane] = f2bf(ea[d]);       // col k = g*16+k16 = lane
        ysumS[wv * 4 + d][col] = acc0[d];
        ysumS[wv * 4 + d][col + 1] = acc1[d];
    }
    __syncthreads();

    // Phase B: ea @ Wea via MFMA (mapping verified in r4's eaz), + relu + store
    const int lm = lane & 15, lq = lane >> 4;
    const short8 af0 = *(const short8*)&eaS[lm][lq * 8];
    const short8 af1 = *(const short8*)&eaS[lm][32 + lq * 8];
    #pragma unroll
    for (int h = 0; h < 2; ++h) {
        const int cg = wv * 2 + h;
        const short8 b0 = *(const short8*)(Wea + (cg * 16 + lm) * 64 + lq * 8);
        const short8 b1 = *(const short8*)(Wea + (cg * 16 + lm) * 64 + 32 + lq * 8);
        f32x4 acc = {0.f, 0.f, 0.f, 0.f};
        acc = __builtin_amdgcn_mfma_f32_16x16x32_bf16(b0, af0, acc, 0, 0, 0);
        acc = __builtin_amdgcn_mfma_f32_16x16x32_bf16(b1, af1, acc, 0, 0, 0);
        const int c0 = cg * 16 + lq * 4;
        const float4 ys = *(const float4*)&ysumS[lm][c0];
        const float4 bv = *(const float4*)(b + c0);
        float4 o;
        o.x = fmaxf(ys.x + acc[0] + bv.x, 0.f);
        o.y = fmaxf(ys.y + acc[1] + bv.y, 0.f);
        o.z = fmaxf(ys.z + acc[2] + bv.z, 0.f);
        o.w = fmaxf(ys.w + acc[3] + bv.w, 0.f);
        *(float4*)(out + (size_t)(row0 + lm) * 128 + c0) = o;
    }
}

extern "C" void kernel_launch(void* const* d_in, const int* in_sizes, int n_in,
                              void* d_out, int out_size, void* d_ws, size_t ws_size,
                              hipStream_t stream)
{
    const float* x         = (const float*)d_in[0];
    const float* edge_attr = (const float*)d_in[1];
    const float* W_rel     = (const float*)d_in[2];
    const float* We_rel    = (const float*)d_in[3];
    const float* W_self    = (const float*)d_in[4];
    const float* b         = (const float*)d_in[5];
    const int*   edge_index= (const int*)d_in[6];
    float* out = (float*)d_out;

    // ws layout (bytes)
    char* wsb = (char*)d_ws;
    unsigned short* zb   = (unsigned short*)wsb;                     //  25,600,000
    unsigned short* y    = (unsigned short*)(wsb + 25600000);        //  76,800,000
    unsigned short* Wt   = (unsigned short*)(wsb + 102400000);       //     131,072
    unsigned short* Wea  = (unsigned short*)(wsb + 102531072);       //      16,384
    unsigned*       cur  = (unsigned*)(wsb + 102547456);             //     400,000
    unsigned*       offs = (unsigned*)(wsb + 102947456);             //     400,004
    unsigned*       bsum = (unsigned*)(wsb + 103347460);             //         512
    uint2*          elist= (uint2*)(wsb + 103347976);                //   4,800,064 (+8 pad)
    unsigned char*  tmp  = (unsigned char*)(wsb + 108148040);        //     600,000

    hipMemsetAsync(cur, 0, NN * sizeof(unsigned), stream);
    prep_kernel<<<1024, 256, 0, stream>>>(W_self, W_rel, We_rel, Wt, Wea,
                                          edge_index, cur, tmp);
    gemm_kernel<<<4096, 256, 0, stream>>>(x, Wt, zb, y);

    scan1_kernel<<<NB1, 256, 0, stream>>>(cur, offs, bsum);
    scan23_kernel<<<NB1, 256, 0, stream>>>(offs, bsum);
    const int eblocks = (NEDGE + 255) / 256;
    fill_kernel <<<eblocks, 256, 0, stream>>>(edge_index, offs, tmp, elist);

    aggregate_kernel<<<NN / 16, 256, 0, stream>>>(zb, y, edge_attr, Wea, b,
                                                  offs, elist, out);
}

// Round 6
// 369.448 us; speedup vs baseline: 1.6511x; 1.6511x over previous
//
#include <hip/hip_runtime.h>

#define NN 100000
#define NE 200000
#define DN 128
#define DE 16
#define NR 3
#define NEDGE (NR * NE)         // 600000
#define NB1 98                  // scan1 blocks: 1024 elems each >= NN
#define NSTRIP 6250             // NN / 16 exactly

typedef __attribute__((ext_vector_type(8))) short short8;
typedef __attribute__((ext_vector_type(4))) float f32x4;

__device__ __forceinline__ unsigned short f2bf(float f) {
    unsigned int u = __float_as_uint(f);
    u = (u + 0x7fffu + ((u >> 16) & 1u)) >> 16;   // RNE
    return (unsigned short)u;
}

// ---------------------------------------------------------------------------
// prep: Wt[m] = bf16(W_m^T), stored PRE-SWIZZLED (chunk XOR) so gemm's LDS
//       copy is linear and ds_read_b128 is bank-conflict-free:
//         Wt[m*16384 + n*128 + ((k>>3)^(n&7))*8 + (k&7)] = bf16(W_m[k][n])
//       Wea[n][k] = bf16(We_{k/16}[k%16][n]) for k<48, 0-pad k=48..63
//       + dst histogram; tmp[eid] = rank within dst (fill needs NO atomics)
// ---------------------------------------------------------------------------
__global__ __launch_bounds__(256) void prep_kernel(
    const float* __restrict__ W_self, const float* __restrict__ W_rel,
    const float* __restrict__ We,
    unsigned short* __restrict__ Wt, unsigned short* __restrict__ Wea,
    const int* __restrict__ ei, unsigned* __restrict__ cur,
    unsigned char* __restrict__ tmp)
{
    const int id = blockIdx.x * 256 + threadIdx.x;   // grid 1024*256 = 262144
    if (id < 65536) {
        const int m = id >> 14, rem = id & 16383;
        const int k = rem >> 7, n = rem & 127;
        const float* src = (m == 0) ? W_self : (W_rel + (size_t)(m - 1) * 16384);
        Wt[m * 16384 + n * 128 + (((k >> 3) ^ (n & 7)) << 3) + (k & 7)] =
            f2bf(src[k * 128 + n]);
    } else if (id < 65536 + 8192) {
        const int wid = id - 65536;
        const int n = wid >> 6, k = wid & 63;
        const float v = (k < 48) ? We[(k >> 4) * 2048 + (k & 15) * 128 + n] : 0.f;
        Wea[n * 64 + k] = f2bf(v);
    }
    const int2* ei2 = (const int2*)ei;
    for (int eid = id; eid < NEDGE; eid += 262144) {
        const int2 e = ei2[eid];
        const unsigned pos = atomicAdd(&cur[e.y], 1u);
        tmp[eid] = (unsigned char)pos;   // max degree ~30 << 256
    }
}

// ---------------------------------------------------------------------------
// MFMA GEMM: x read ONCE (A-frags held in registers across the m-loop),
//   B staged per-matrix into LDS inside the block.
//   Block = 4 waves; wave w owns strips slot=bid*4+w and 4096+slot (<6250).
//   m-loop: stage Wt[m] (pre-swizzled) -> barrier -> 32 MFMA per strip with
//   XOR-swizzled ds_read_b128 (<=2-way banks) -> stores -> barrier.
//   ~90 VGPR, 32 KB LDS -> ~4 blocks/CU (16 waves/CU).
// ---------------------------------------------------------------------------
__global__ __launch_bounds__(256, 4) void gemm_kernel(
    const float* __restrict__ x,
    const unsigned short* __restrict__ Wt,
    unsigned short* __restrict__ zb,
    unsigned short* __restrict__ y)
{
    __shared__ __align__(16) unsigned short Bs[128 * 128];   // 32 KB
    const int tid = threadIdx.x;
    const int w = tid >> 6;
    const int lane = tid & 63;
    const int lm = lane & 15;
    const int lq = lane >> 4;
    const int slot = blockIdx.x * 4 + w;        // 0..4095
    const int s1 = slot;
    const int s2 = (slot < NSTRIP - 4096) ? (4096 + slot) : -1;
    const int scount = (s2 >= 0) ? 2 : 1;

    // A fragments for this wave's strips: load fp32, convert once, keep in regs
    short8 af[2][4];
    for (int t = 0; t < scount; ++t) {
        const int s = t ? s2 : s1;
        const float* xp = x + (size_t)(s * 16 + lm) * 128 + lq * 8;
        #pragma unroll
        for (int ks = 0; ks < 4; ++ks) {
            const float4 v0 = *(const float4*)(xp + ks * 32);
            const float4 v1 = *(const float4*)(xp + ks * 32 + 4);
            short8 tt;
            tt[0] = f2bf(v0.x); tt[1] = f2bf(v0.y); tt[2] = f2bf(v0.z); tt[3] = f2bf(v0.w);
            tt[4] = f2bf(v1.x); tt[5] = f2bf(v1.y); tt[6] = f2bf(v1.z); tt[7] = f2bf(v1.w);
            af[t][ks] = tt;
        }
    }

    for (int m = 0; m < 4; ++m) {
        // stage matrix m (linear copy; array is pre-swizzled in global, L2-hot)
        {
            const uint4* wp4 = (const uint4*)(Wt + (size_t)m * 16384);
            #pragma unroll
            for (int i = 0; i < 8; ++i)
                *(uint4*)&Bs[(size_t)(tid + i * 256) * 8] = wp4[tid + i * 256];
        }
        __syncthreads();

        unsigned short* outp = (m == 0) ? zb : (y + (size_t)(m - 1) * NN * 128);
        for (int t = 0; t < scount; ++t) {
            const int s = t ? s2 : s1;
            f32x4 acc[8];
            #pragma unroll
            for (int cg = 0; cg < 8; ++cg) acc[cg] = (f32x4){0.f, 0.f, 0.f, 0.f};
            #pragma unroll
            for (int cg = 0; cg < 8; ++cg)
                #pragma unroll
                for (int ks = 0; ks < 4; ++ks) {
                    // logical B row n=cg*16+lm, chunk ks*4+lq, XOR-swizzled
                    const short8 bf = *(const short8*)
                        &Bs[(cg * 16 + lm) * 128 + (((ks * 4 + lq) ^ (lm & 7)) << 3)];
                    acc[cg] = __builtin_amdgcn_mfma_f32_16x16x32_bf16(bf, af[t][ks], acc[cg], 0, 0, 0);
                }
            unsigned short* rp = outp + (size_t)(s * 16 + lm) * 128 + lq * 4;
            #pragma unroll
            for (int cg = 0; cg < 8; ++cg) {
                ushort4 o;
                o.x = f2bf(acc[cg][0]); o.y = f2bf(acc[cg][1]);
                o.z = f2bf(acc[cg][2]); o.w = f2bf(acc[cg][3]);
                *(ushort4*)(rp + cg * 16) = o;
            }
        }
        __syncthreads();   // Bs overwritten next m
    }
}

// ---------------------------------------------------------------------------
// CSR build: scan1 + merged scan2/3
// ---------------------------------------------------------------------------
__global__ __launch_bounds__(256) void scan1_kernel(
    const unsigned* __restrict__ cnt, unsigned* __restrict__ offs,
    unsigned* __restrict__ bsum)
{
    __shared__ unsigned wtot[4];
    const int tid = threadIdx.x, lane = tid & 63, wv = tid >> 6;
    const int base = blockIdx.x * 1024 + tid * 4;
    unsigned c[4];
    #pragma unroll
    for (int j = 0; j < 4; ++j) c[j] = (base + j < NN) ? cnt[base + j] : 0u;
    const unsigned ts = c[0] + c[1] + c[2] + c[3];
    unsigned incl = ts;
    #pragma unroll
    for (int d = 1; d < 64; d <<= 1) {
        unsigned v = __shfl_up(incl, d, 64);
        if (lane >= d) incl += v;
    }
    if (lane == 63) wtot[wv] = incl;
    __syncthreads();
    unsigned woff = 0;
    for (int p = 0; p < 4; ++p) if (p < wv) woff += wtot[p];
    unsigned run = woff + incl - ts;
    #pragma unroll
    for (int j = 0; j < 4; ++j) {
        if (base + j < NN) offs[base + j] = run;
        run += c[j];
    }
    if (tid == 255) bsum[blockIdx.x] = woff + incl;
}

__global__ __launch_bounds__(256) void scan23_kernel(
    unsigned* __restrict__ offs, const unsigned* __restrict__ bsum)
{
    __shared__ unsigned add_s;
    const int tid = threadIdx.x;
    if (tid < 64) {
        const int lane = tid;
        const unsigned v0 = (2 * lane     < NB1) ? bsum[2 * lane]     : 0u;
        const unsigned v1 = (2 * lane + 1 < NB1) ? bsum[2 * lane + 1] : 0u;
        const unsigned s = v0 + v1;
        unsigned incl = s;
        #pragma unroll
        for (int d = 1; d < 64; d <<= 1) {
            unsigned t = __shfl_up(incl, d, 64);
            if (lane >= d) incl += t;
        }
        const unsigned run = incl - s;           // exclusive prefix at 2*lane
        if (lane == (blockIdx.x >> 1))
            add_s = (blockIdx.x & 1) ? (run + v0) : run;
    }
    __syncthreads();
    const unsigned add = add_s;
    const int base = blockIdx.x * 1024 + tid * 4;
    #pragma unroll
    for (int j = 0; j < 4; ++j)
        if (base + j < NN) offs[base + j] += add;
    if (blockIdx.x == 0 && tid == 0) offs[NN] = NEDGE;
}

__global__ __launch_bounds__(256) void fill_kernel(
    const int* __restrict__ ei, const unsigned* __restrict__ offs,
    const unsigned char* __restrict__ tmp, uint2* __restrict__ elist)
{
    const int eid = blockIdx.x * 256 + threadIdx.x;
    if (eid < NEDGE) {
        const int2 e = ((const int2*)ei)[eid];
        const unsigned r = (eid >= 2 * NE) ? 2u : (eid >= NE ? 1u : 0u);
        const unsigned pos = offs[e.y] + (unsigned)tmp[eid];
        elist[pos] = make_uint2(r * NN + (unsigned)e.x, (unsigned)eid);
    }
}

// ---------------------------------------------------------------------------
// Fused aggregate (y-gather + ea-reduce + ea@We MFMA + relu):  unchanged r5
// ---------------------------------------------------------------------------
__global__ __launch_bounds__(256, 4) void aggregate_kernel(
    const unsigned short* __restrict__ zb,
    const unsigned short* __restrict__ y,      // [3*NN][128] bf16
    const float* __restrict__ edge_attr,       // [NEDGE][16]
    const unsigned short* __restrict__ Wea,    // [128][64] bf16
    const float* __restrict__ b,
    const unsigned* __restrict__ offs,         // [NN+1]
    const uint2* __restrict__ elist,
    float* __restrict__ out)
{
    __shared__ __align__(16) unsigned short eaS[16][72];
    __shared__ __align__(16) float ysumS[16][132];
    const int tid = threadIdx.x;
    const int wv = tid >> 6, lane = tid & 63;
    const int row0 = blockIdx.x * 16;             // grid 6250, exact
    const int dst0 = row0 + wv * 4;
    const int col = 2 * lane;
    const int k16 = lane & 15;
    const int g = lane >> 4;                      // rel group; 3 = zero pad

    unsigned sI[4], eI[4];
    #pragma unroll
    for (int d = 0; d < 4; ++d) {
        sI[d] = __builtin_amdgcn_readfirstlane(offs[dst0 + d]);
        eI[d] = __builtin_amdgcn_readfirstlane(offs[dst0 + d + 1]);
    }

    unsigned r[4][8], q[4][8];
    #pragma unroll
    for (int d = 0; d < 4; ++d) {
        const uint2* ep = elist + sI[d];          // +8 pad allocated
        #pragma unroll
        for (int j = 0; j < 8; ++j) {
            const uint2 p = ep[j];
            r[d][j] = (p.x < 3u * NN) ? p.x : 0u;
            q[d][j] = (p.y < (unsigned)NEDGE) ? p.y : 0u;
        }
    }

    unsigned v[4][8];
    #pragma unroll
    for (int d = 0; d < 4; ++d)
        #pragma unroll
        for (int j = 0; j < 8; ++j)
            v[d][j] = *(const unsigned*)(y + (size_t)r[d][j] * 128 + col);
    float a[4][8];
    #pragma unroll
    for (int d = 0; d < 4; ++d)
        #pragma unroll
        for (int j = 0; j < 8; ++j)
            a[d][j] = edge_attr[(size_t)q[d][j] * 16 + k16];

    float acc0[4], acc1[4], ea[4];
    #pragma unroll
    for (int d = 0; d < 4; ++d) {
        const unsigned zv = *(const unsigned*)(zb + (size_t)(dst0 + d) * 128 + col);
        acc0[d] = __uint_as_float(zv << 16);
        acc1[d] = __uint_as_float(zv & 0xffff0000u);
        ea[d] = 0.f;
    }

    #pragma unroll
    for (int d = 0; d < 4; ++d)
        #pragma unroll
        for (int j = 0; j < 8; ++j) {
            const bool live = (sI[d] + (unsigned)j) < eI[d];
            const unsigned vv = live ? v[d][j] : 0u;
            acc0[d] += __uint_as_float(vv << 16);
            acc1[d] += __uint_as_float(vv & 0xffff0000u);
            const bool okr = live && q[d][j] >= (unsigned)(g * NE)
                                  && q[d][j] < (unsigned)((g + 1) * NE);
            ea[d] += okr ? a[d][j] : 0.f;
        }

    #pragma unroll
    for (int d = 0; d < 4; ++d)
        for (unsigned i = sI[d] + 8; i < eI[d]; ++i) {
            const uint2 p = elist[i];
            const unsigned vv = *(const unsigned*)(y + (size_t)p.x * 128 + col);
            const float aa = edge_attr[(size_t)p.y * 16 + k16];
            acc0[d] += __uint_as_float(vv << 16);
            acc1[d] += __uint_as_float(vv & 0xffff0000u);
            const bool okr = p.y >= (unsigned)(g * NE) && p.y < (unsigned)((g + 1) * NE);
            ea[d] += okr ? aa : 0.f;
        }

    #pragma unroll
    for (int d = 0; d < 4; ++d) {
        eaS[wv * 4 + d][lane] = f2bf(ea[d]);       // col k = g*16+k16 = lane
        ysumS[wv * 4 + d][col] = acc0[d];
        ysumS[wv * 4 + d][col + 1] = acc1[d];
    }
    __syncthreads();

    const int lm = lane & 15, lq = lane >> 4;
    const short8 af0 = *(const short8*)&eaS[lm][lq * 8];
    const short8 af1 = *(const short8*)&eaS[lm][32 + lq * 8];
    #pragma unroll
    for (int h = 0; h < 2; ++h) {
        const int cg = wv * 2 + h;
        const short8 b0 = *(const short8*)(Wea + (cg * 16 + lm) * 64 + lq * 8);
        const short8 b1 = *(const short8*)(Wea + (cg * 16 + lm) * 64 + 32 + lq * 8);
        f32x4 acc = {0.f, 0.f, 0.f, 0.f};
        acc = __builtin_amdgcn_mfma_f32_16x16x32_bf16(b0, af0, acc, 0, 0, 0);
        acc = __builtin_amdgcn_mfma_f32_16x16x32_bf16(b1, af1, acc, 0, 0, 0);
        const int c0 = cg * 16 + lq * 4;
        const float4 ys = *(const float4*)&ysumS[lm][c0];
        const float4 bv = *(const float4*)(b + c0);
        float4 o;
        o.x = fmaxf(ys.x + acc[0] + bv.x, 0.f);
        o.y = fmaxf(ys.y + acc[1] + bv.y, 0.f);
        o.z = fmaxf(ys.z + acc[2] + bv.z, 0.f);
        o.w = fmaxf(ys.w + acc[3] + bv.w, 0.f);
        *(float4*)(out + (size_t)(row0 + lm) * 128 + c0) = o;
    }
}

extern "C" void kernel_launch(void* const* d_in, const int* in_sizes, int n_in,
                              void* d_out, int out_size, void* d_ws, size_t ws_size,
                              hipStream_t stream)
{
    const float* x         = (const float*)d_in[0];
    const float* edge_attr = (const float*)d_in[1];
    const float* W_rel     = (const float*)d_in[2];
    const float* We_rel    = (const float*)d_in[3];
    const float* W_self    = (const float*)d_in[4];
    const float* b         = (const float*)d_in[5];
    const int*   edge_index= (const int*)d_in[6];
    float* out = (float*)d_out;

    // ws layout (bytes)
    char* wsb = (char*)d_ws;
    unsigned short* zb   = (unsigned short*)wsb;                     //  25,600,000
    unsigned short* y    = (unsigned short*)(wsb + 25600000);        //  76,800,000
    unsigned short* Wt   = (unsigned short*)(wsb + 102400000);       //     131,072
    unsigned short* Wea  = (unsigned short*)(wsb + 102531072);       //      16,384
    unsigned*       cur  = (unsigned*)(wsb + 102547456);             //     400,000
    unsigned*       offs = (unsigned*)(wsb + 102947456);             //     400,004
    unsigned*       bsum = (unsigned*)(wsb + 103347460);             //         512
    uint2*          elist= (uint2*)(wsb + 103347976);                //   4,800,064 (+8 pad)
    unsigned char*  tmp  = (unsigned char*)(wsb + 108148040);        //     600,000

    hipMemsetAsync(cur, 0, NN * sizeof(unsigned), stream);
    prep_kernel<<<1024, 256, 0, stream>>>(W_self, W_rel, We_rel, Wt, Wea,
                                          edge_index, cur, tmp);
    gemm_kernel<<<1024, 256, 0, stream>>>(x, Wt, zb, y);

    scan1_kernel<<<NB1, 256, 0, stream>>>(cur, offs, bsum);
    scan23_kernel<<<NB1, 256, 0, stream>>>(offs, bsum);
    const int eblocks = (NEDGE + 255) / 256;
    fill_kernel <<<eblocks, 256, 0, stream>>>(edge_index, offs, tmp, elist);

    aggregate_kernel<<<NN / 16, 256, 0, stream>>>(zb, y, edge_attr, Wea, b,
                                                  offs, elist, out);
}

// Round 7
// 276.025 us; speedup vs baseline: 2.2099x; 1.3385x over previous
//
#include <hip/hip_runtime.h>

#define NN 100000
#define NE 200000
#define DN 128
#define DE 16
#define NR 3
#define NEDGE (NR * NE)         // 600000
#define NB1 98                  // scan1 blocks: 1024 elems each >= NN
#define NSTRIP 6250             // NN / 16 exactly

typedef __attribute__((ext_vector_type(8))) short short8;
typedef __attribute__((ext_vector_type(4))) float f32x4;

__device__ __forceinline__ unsigned short f2bf(float f) {
    unsigned int u = __float_as_uint(f);
    u = (u + 0x7fffu + ((u >> 16) & 1u)) >> 16;   // RNE
    return (unsigned short)u;
}

// ---------------------------------------------------------------------------
// prep: Wall[m] = bf16 B-matrices, PRE-SWIZZLED (chunk XOR) for LDS staging:
//         m=0: W_self^T   m=1..3: W_rel^T   m=4: We padded to [128][128]
//         Wall[m*16384 + n*128 + ((k>>3)^(n&7))*8 + (k&7)] = bf16(W_m[k][n])
//         (m=4: row k = g*16+k16 -> We[g][k16][n] for k<48, else 0)
//       + dst histogram; tmp[eid] = rank within dst (fill needs NO atomics)
// ---------------------------------------------------------------------------
__global__ __launch_bounds__(256) void prep_kernel(
    const float* __restrict__ W_self, const float* __restrict__ W_rel,
    const float* __restrict__ We,
    unsigned short* __restrict__ Wall,
    const int* __restrict__ ei, unsigned* __restrict__ cur,
    unsigned char* __restrict__ tmp)
{
    const int id = blockIdx.x * 256 + threadIdx.x;   // grid 1024*256 = 262144
    if (id < 81920) {
        const int m = id >> 14, rem = id & 16383;
        const int k = rem >> 7, n = rem & 127;
        float v;
        if (m == 0)      v = W_self[k * 128 + n];
        else if (m < 4)  v = W_rel[(size_t)(m - 1) * 16384 + k * 128 + n];
        else             v = (k < 48) ? We[(k >> 4) * 2048 + (k & 15) * 128 + n] : 0.f;
        Wall[m * 16384 + n * 128 + (((k >> 3) ^ (n & 7)) << 3) + (k & 7)] = f2bf(v);
    }
    const int2* ei2 = (const int2*)ei;
    for (int eid = id; eid < NEDGE; eid += 262144) {
        const int2 e = ei2[eid];
        const unsigned pos = atomicAdd(&cur[e.y], 1u);
        tmp[eid] = (unsigned char)pos;   // max degree ~30 << 256
    }
}

// ---------------------------------------------------------------------------
// CSR build: scan1 + merged scan2/3
// ---------------------------------------------------------------------------
__global__ __launch_bounds__(256) void scan1_kernel(
    const unsigned* __restrict__ cnt, unsigned* __restrict__ offs,
    unsigned* __restrict__ bsum)
{
    __shared__ unsigned wtot[4];
    const int tid = threadIdx.x, lane = tid & 63, wv = tid >> 6;
    const int base = blockIdx.x * 1024 + tid * 4;
    unsigned c[4];
    #pragma unroll
    for (int j = 0; j < 4; ++j) c[j] = (base + j < NN) ? cnt[base + j] : 0u;
    const unsigned ts = c[0] + c[1] + c[2] + c[3];
    unsigned incl = ts;
    #pragma unroll
    for (int d = 1; d < 64; d <<= 1) {
        unsigned v = __shfl_up(incl, d, 64);
        if (lane >= d) incl += v;
    }
    if (lane == 63) wtot[wv] = incl;
    __syncthreads();
    unsigned woff = 0;
    for (int p = 0; p < 4; ++p) if (p < wv) woff += wtot[p];
    unsigned run = woff + incl - ts;
    #pragma unroll
    for (int j = 0; j < 4; ++j) {
        if (base + j < NN) offs[base + j] = run;
        run += c[j];
    }
    if (tid == 255) bsum[blockIdx.x] = woff + incl;
}

__global__ __launch_bounds__(256) void scan23_kernel(
    unsigned* __restrict__ offs, const unsigned* __restrict__ bsum)
{
    __shared__ unsigned add_s;
    const int tid = threadIdx.x;
    if (tid < 64) {
        const int lane = tid;
        const unsigned v0 = (2 * lane     < NB1) ? bsum[2 * lane]     : 0u;
        const unsigned v1 = (2 * lane + 1 < NB1) ? bsum[2 * lane + 1] : 0u;
        const unsigned s = v0 + v1;
        unsigned incl = s;
        #pragma unroll
        for (int d = 1; d < 64; d <<= 1) {
            unsigned t = __shfl_up(incl, d, 64);
            if (lane >= d) incl += t;
        }
        const unsigned run = incl - s;           // exclusive prefix at 2*lane
        if (lane == (blockIdx.x >> 1))
            add_s = (blockIdx.x & 1) ? (run + v0) : run;
    }
    __syncthreads();
    const unsigned add = add_s;
    const int base = blockIdx.x * 1024 + tid * 4;
    #pragma unroll
    for (int j = 0; j < 4; ++j)
        if (base + j < NN) offs[base + j] += add;
    if (blockIdx.x == 0 && tid == 0) offs[NN] = NEDGE;
}

__global__ __launch_bounds__(256) void fill_kernel(
    const int* __restrict__ ei, const unsigned* __restrict__ offs,
    const unsigned char* __restrict__ tmp, uint2* __restrict__ elist)
{
    const int eid = blockIdx.x * 256 + threadIdx.x;
    if (eid < NEDGE) {
        const int2 e = ((const int2*)ei)[eid];
        const unsigned pos = offs[e.y] + (unsigned)tmp[eid];
        elist[pos] = make_uint2((unsigned)e.x, (unsigned)eid);  // (src, eid)
    }
}

// ---------------------------------------------------------------------------
// gather: per-dst per-relation x-row sums (linearity: sum first, W later).
//   Block = 4 waves = 16 dsts; wave = 4 dsts, processed in d-pairs (reg cap).
//   x gathers hit L3 (x = 51 MB resident); elist/offs via scalar loads.
//   Writes: sbuf[rel][dst][128] bf16 (streaming), eap[dst][128] bf16
//   (ea col k = g*16+k16; cols 48..127 zero -> uniform K=128 phase in gemm2).
// ---------------------------------------------------------------------------
__global__ __launch_bounds__(256, 4) void gather_kernel(
    const float* __restrict__ x,
    const float* __restrict__ edge_attr,       // [NEDGE][16]
    const unsigned* __restrict__ offs,         // [NN+1]
    const uint2* __restrict__ elist,           // (src, eid), +8 pad
    unsigned short* __restrict__ sbuf,         // [3*NN][128] bf16
    unsigned short* __restrict__ eap)          // [NN][128] bf16
{
    const int tid = threadIdx.x;
    const int wv = tid >> 6, lane = tid & 63;
    const int dst0 = (blockIdx.x * 4 + wv) * 4;   // grid 6250, exact
    const int col = 2 * lane;
    const int k16 = lane & 15;
    const int g = lane >> 4;                      // rel group; 3 = zero pad

    unsigned sI[4], eI[4];
    #pragma unroll
    for (int d = 0; d < 4; ++d) {
        sI[d] = __builtin_amdgcn_readfirstlane(offs[dst0 + d]);
        eI[d] = __builtin_amdgcn_readfirstlane(offs[dst0 + d + 1]);
    }

    float sc0[4][3], sc1[4][3], ea[4];
    #pragma unroll
    for (int d = 0; d < 4; ++d) {
        ea[d] = 0.f;
        #pragma unroll
        for (int r = 0; r < 3; ++r) { sc0[d][r] = 0.f; sc1[d][r] = 0.f; }
    }

    #pragma unroll
    for (int pair = 0; pair < 2; ++pair) {
        unsigned src[2][8], q[2][8];
        #pragma unroll
        for (int dd = 0; dd < 2; ++dd) {
            const int d = pair * 2 + dd;
            const uint2* ep = elist + sI[d];
            #pragma unroll
            for (int j = 0; j < 8; ++j) {
                const uint2 p = ep[j];
                src[dd][j] = (p.x < (unsigned)NN) ? p.x : 0u;
                q[dd][j]   = (p.y < (unsigned)NEDGE) ? p.y : 0u;
            }
        }
        float2 xv[2][8];
        #pragma unroll
        for (int dd = 0; dd < 2; ++dd)
            #pragma unroll
            for (int j = 0; j < 8; ++j)
                xv[dd][j] = *(const float2*)(x + (size_t)src[dd][j] * 128 + col);
        float a[2][8];
        #pragma unroll
        for (int dd = 0; dd < 2; ++dd)
            #pragma unroll
            for (int j = 0; j < 8; ++j)
                a[dd][j] = edge_attr[(size_t)q[dd][j] * 16 + k16];
        #pragma unroll
        for (int dd = 0; dd < 2; ++dd)
            #pragma unroll
            for (int j = 0; j < 8; ++j) {
                const int d = pair * 2 + dd;
                const bool live = (sI[d] + (unsigned)j) < eI[d];
                const unsigned uq = q[dd][j];
                const bool m0 = live && (uq < (unsigned)NE);
                const bool m1 = live && (uq >= (unsigned)NE) && (uq < 2u * NE);
                const bool m2 = live && (uq >= 2u * NE);
                sc0[d][0] += m0 ? xv[dd][j].x : 0.f;
                sc1[d][0] += m0 ? xv[dd][j].y : 0.f;
                sc0[d][1] += m1 ? xv[dd][j].x : 0.f;
                sc1[d][1] += m1 ? xv[dd][j].y : 0.f;
                sc0[d][2] += m2 ? xv[dd][j].x : 0.f;
                sc1[d][2] += m2 ? xv[dd][j].y : 0.f;
                const bool okr = live && uq >= (unsigned)(g * NE)
                                      && uq < (unsigned)((g + 1) * NE);
                ea[d] += okr ? a[dd][j] : 0.f;
            }
    }

    // tails (deg > 8)
    #pragma unroll
    for (int d = 0; d < 4; ++d)
        for (unsigned i = sI[d] + 8; i < eI[d]; ++i) {
            const uint2 p = elist[i];
            const float2 xv = *(const float2*)(x + (size_t)p.x * 128 + col);
            const float av = edge_attr[(size_t)p.y * 16 + k16];
            const bool m0 = p.y < (unsigned)NE;
            const bool m2 = p.y >= 2u * NE;
            const bool m1 = !m0 && !m2;
            sc0[d][0] += m0 ? xv.x : 0.f;  sc1[d][0] += m0 ? xv.y : 0.f;
            sc0[d][1] += m1 ? xv.x : 0.f;  sc1[d][1] += m1 ? xv.y : 0.f;
            sc0[d][2] += m2 ? xv.x : 0.f;  sc1[d][2] += m2 ? xv.y : 0.f;
            const bool okr = p.y >= (unsigned)(g * NE) && p.y < (unsigned)((g + 1) * NE);
            ea[d] += okr ? av : 0.f;
        }

    #pragma unroll
    for (int d = 0; d < 4; ++d) {
        const int dst = dst0 + d;
        #pragma unroll
        for (int r = 0; r < 3; ++r) {
            const unsigned pk = (unsigned)f2bf(sc0[d][r])
                              | ((unsigned)f2bf(sc1[d][r]) << 16);
            *(unsigned*)(sbuf + ((size_t)r * NN + dst) * 128 + col) = pk;
        }
        eap[(size_t)dst * 128 + lane] = f2bf(ea[d]);   // lanes 48..63: ea==0
        eap[(size_t)dst * 128 + 64 + lane] = 0;
    }
}

// ---------------------------------------------------------------------------
// gemm2: out = relu([x | s1 | s2 | s3 | ea] @ Wall + b), K = 5*128.
//   Block 256 = 4 waves, wave = one 16-row strip; acc[8] persists across the
//   5 phases; per phase Wall[m] staged to LDS (32 KB, XOR-swizzled ds_read),
//   A-frags loaded streaming (x f32-converted for m=0, bf16 else).
//   Eliminates y and zb buffers entirely; single f32 out write.
// ---------------------------------------------------------------------------
__global__ __launch_bounds__(256, 3) void gemm2_kernel(
    const float* __restrict__ x,
    const unsigned short* __restrict__ sbuf,
    const unsigned short* __restrict__ eap,
    const unsigned short* __restrict__ Wall,
    const float* __restrict__ b,
    float* __restrict__ out)
{
    __shared__ __align__(16) unsigned short Bs[128 * 128];   // 32 KB
    const int tid = threadIdx.x;
    const int w = tid >> 6;
    const int lane = tid & 63;
    const int lm = lane & 15;
    const int lq = lane >> 4;
    const int strip = blockIdx.x * 4 + w;       // grid 1563 -> 0..6251
    const bool act = strip < NSTRIP;
    const int row = act ? (strip * 16 + lm) : 0;

    f32x4 acc[8];
    #pragma unroll
    for (int cg = 0; cg < 8; ++cg) acc[cg] = (f32x4){0.f, 0.f, 0.f, 0.f};

    for (int m = 0; m < 5; ++m) {
        {
            const uint4* wp4 = (const uint4*)(Wall + (size_t)m * 16384);
            #pragma unroll
            for (int i = 0; i < 8; ++i)
                *(uint4*)&Bs[(size_t)(tid + i * 256) * 8] = wp4[tid + i * 256];
        }
        __syncthreads();

        if (act) {
            short8 af[4];
            if (m == 0) {
                const float* xp = x + (size_t)row * 128 + lq * 8;
                #pragma unroll
                for (int ks = 0; ks < 4; ++ks) {
                    const float4 v0 = *(const float4*)(xp + ks * 32);
                    const float4 v1 = *(const float4*)(xp + ks * 32 + 4);
                    short8 t;
                    t[0] = f2bf(v0.x); t[1] = f2bf(v0.y); t[2] = f2bf(v0.z); t[3] = f2bf(v0.w);
                    t[4] = f2bf(v1.x); t[5] = f2bf(v1.y); t[6] = f2bf(v1.z); t[7] = f2bf(v1.w);
                    af[ks] = t;
                }
            } else {
                const unsigned short* ap = (m < 4)
                    ? (sbuf + ((size_t)(m - 1) * NN + row) * 128)
                    : (eap + (size_t)row * 128);
                #pragma unroll
                for (int ks = 0; ks < 4; ++ks)
                    af[ks] = *(const short8*)(ap + ks * 32 + lq * 8);
            }
            #pragma unroll
            for (int cg = 0; cg < 8; ++cg)
                #pragma unroll
                for (int ks = 0; ks < 4; ++ks) {
                    const short8 bf = *(const short8*)
                        &Bs[(cg * 16 + lm) * 128 + (((ks * 4 + lq) ^ (lm & 7)) << 3)];
                    acc[cg] = __builtin_amdgcn_mfma_f32_16x16x32_bf16(bf, af[ks], acc[cg], 0, 0, 0);
                }
        }
        __syncthreads();   // Bs overwritten next m
    }

    if (act) {
        float* rp = out + (size_t)row * 128;
        #pragma unroll
        for (int cg = 0; cg < 8; ++cg) {
            const int c0 = cg * 16 + lq * 4;
            const float4 bv = *(const float4*)(b + c0);
            float4 o;
            o.x = fmaxf(acc[cg][0] + bv.x, 0.f);
            o.y = fmaxf(acc[cg][1] + bv.y, 0.f);
            o.z = fmaxf(acc[cg][2] + bv.z, 0.f);
            o.w = fmaxf(acc[cg][3] + bv.w, 0.f);
            *(float4*)(rp + c0) = o;
        }
    }
}

extern "C" void kernel_launch(void* const* d_in, const int* in_sizes, int n_in,
                              void* d_out, int out_size, void* d_ws, size_t ws_size,
                              hipStream_t stream)
{
    const float* x         = (const float*)d_in[0];
    const float* edge_attr = (const float*)d_in[1];
    const float* W_rel     = (const float*)d_in[2];
    const float* We_rel    = (const float*)d_in[3];
    const float* W_self    = (const float*)d_in[4];
    const float* b         = (const float*)d_in[5];
    const int*   edge_index= (const int*)d_in[6];
    float* out = (float*)d_out;

    // ws layout (bytes)
    char* wsb = (char*)d_ws;
    unsigned short* sbuf = (unsigned short*)wsb;                     //  76,800,000
    unsigned short* eap  = (unsigned short*)(wsb + 76800000);        //  25,600,000
    unsigned char*  tmp  = (unsigned char*)(wsb + 76800000);         // ALIAS eap:
                                                                     // tmp dead before gather writes eap
    unsigned short* Wall = (unsigned short*)(wsb + 102400000);       //     163,840
    unsigned*       cur  = (unsigned*)(wsb + 102563840);             //     400,000
    unsigned*       offs = (unsigned*)(wsb + 102963840);             //     400,004
    unsigned*       bsum = (unsigned*)(wsb + 103363848);             //         512
    uint2*          elist= (uint2*)(wsb + 103364360);                //   4,800,064 (+8 pad)

    hipMemsetAsync(cur, 0, NN * sizeof(unsigned), stream);
    prep_kernel<<<1024, 256, 0, stream>>>(W_self, W_rel, We_rel, Wall,
                                          edge_index, cur, tmp);
    scan1_kernel<<<NB1, 256, 0, stream>>>(cur, offs, bsum);
    scan23_kernel<<<NB1, 256, 0, stream>>>(offs, bsum);
    const int eblocks = (NEDGE + 255) / 256;
    fill_kernel <<<eblocks, 256, 0, stream>>>(edge_index, offs, tmp, elist);

    gather_kernel<<<NN / 16, 256, 0, stream>>>(x, edge_attr, offs, elist,
                                               sbuf, eap);
    gemm2_kernel<<<(NSTRIP + 3) / 4, 256, 0, stream>>>(x, sbuf, eap, Wall,
                                                       b, out);
}